// Round 7
// baseline (206.755 us; speedup 1.0000x reference)
//
#include <hip/hip_runtime.h>
#include <hip/hip_cooperative_groups.h>

namespace cg = cooperative_groups;

#define NTRAIN 200000
#define NB     256
#define BIT    64
#define MAXS   30
#define NCLS   100
#define EPB    4            // pool entries per pair block
#define CHUNK  4096
#define PERT   16
#define NREG   16           // regularizer blocks
#define GRID_N 800          // pair blocks = 100 classes x 8 entry-chunks
#define MVAL   128.0f
#define ALPHA  0.01f

struct Ws {
    int   pool[NCLS][32];
    int   povr[NCLS][32];
    int   cnt[NCLS];
    int   mult[NCLS];
    int   cntw[NCLS];       // mult * cnt
    float partial[GRID_N];
    float regp[NREG];
};

struct ShMem {
    int   addl[NB];
    int   reml[NB];
    int   pool[MAXS];
    int   povr[MAXS];
    float up[EPB * BIT];
    int   wsA[4], wsB[4], wsC[4];
    float redf[4], redg[4];
    int   redi[4];
};

__device__ __forceinline__ unsigned matchbits16(float4 a, float4 b, float4 c4,
                                                float4 d, float cf) {
    unsigned mb = 0;
    if (a.x  == cf) mb |= 1u << 0;
    if (a.y  == cf) mb |= 1u << 1;
    if (a.z  == cf) mb |= 1u << 2;
    if (a.w  == cf) mb |= 1u << 3;
    if (b.x  == cf) mb |= 1u << 4;
    if (b.y  == cf) mb |= 1u << 5;
    if (b.z  == cf) mb |= 1u << 6;
    if (b.w  == cf) mb |= 1u << 7;
    if (c4.x == cf) mb |= 1u << 8;
    if (c4.y == cf) mb |= 1u << 9;
    if (c4.z == cf) mb |= 1u << 10;
    if (c4.w == cf) mb |= 1u << 11;
    if (d.x  == cf) mb |= 1u << 12;
    if (d.y  == cf) mb |= 1u << 13;
    if (d.z  == cf) mb |= 1u << 14;
    if (d.w  == cf) mb |= 1u << 15;
    return mb;
}

// ---- Phase A (class block): scan for first-MAXS ascending pool of class c
// over the virtually-scattered bank; store pool/povr/cnt/mult to ws. ----
__device__ __forceinline__ void phaseA_class(
    int c, int t, const int* __restrict__ y, const int* __restrict__ ind,
    const float* __restrict__ Y, Ws* __restrict__ ws, ShMem& sh)
{
    const int lane = t & 63, wave = t >> 6;
    const float cf = (float)c;

    const int myi = ind[t];
    const int myy = y[t];
    const int s0  = t * PERT;
    float4 yv0, yv1, yv2, yv3;          // Y chunk 0, prefetched
    {
        const float4* yp = (const float4*)(Y + s0);
        yv0 = yp[0]; yv1 = yp[1]; yv2 = yp[2]; yv3 = yp[3];
    }
    const float ybank = Y[myi];

    const bool ismem = (myy == c);
    const bool fneg  = ismem && (ybank != cf);    // becomes class c
    const bool fpos  = (!ismem) && (ybank == cf); // stops being class c
    unsigned long long balm = __ballot(ismem);
    unsigned long long bala = __ballot(fneg);
    unsigned long long balr = __ballot(fpos);
    if (lane == 0) {
        sh.wsA[wave] = (int)__popcll(balm);
        sh.wsB[wave] = (int)__popcll(bala);
        sh.wsC[wave] = (int)__popcll(balr);
    }
    __syncthreads();
    const int mult = sh.wsA[0] + sh.wsA[1] + sh.wsA[2] + sh.wsA[3];
    if (mult == 0) {                    // block-uniform
        if (t == 0) { ws->cnt[c] = 0; ws->mult[c] = 0; ws->cntw[c] = 0; }
        return;
    }
    const int nadd = sh.wsB[0] + sh.wsB[1] + sh.wsB[2] + sh.wsB[3];
    const int nrem = sh.wsC[0] + sh.wsC[1] + sh.wsC[2] + sh.wsC[3];
    int pa = 0, pr = 0;
    #pragma unroll
    for (int w = 0; w < 4; ++w) if (w < wave) { pa += sh.wsB[w]; pr += sh.wsC[w]; }
    const unsigned long long lm = (1ull << lane) - 1ull;
    if (fneg) sh.addl[pa + (int)__popcll(bala & lm)] = myi;
    if (fpos) sh.reml[pr + (int)__popcll(balr & lm)] = myi;
    __syncthreads();

    // ---- chunk 0 (prefetched) ----
    unsigned mbits = matchbits16(yv0, yv1, yv2, yv3, cf);
    for (int a2 = 0; a2 < nadd; ++a2) {
        unsigned rel = (unsigned)(sh.addl[a2] - s0);
        if (rel < (unsigned)PERT) mbits |= 1u << rel;
    }
    for (int r2 = 0; r2 < nrem; ++r2) {
        unsigned rel = (unsigned)(sh.reml[r2] - s0);
        if (rel < (unsigned)PERT) mbits &= ~(1u << rel);
    }
    const int mcnt = __popc(mbits);
    int x = mcnt;                       // ordered inclusive wave scan
    #pragma unroll
    for (int off = 1; off < 64; off <<= 1) {
        int v2 = __shfl_up(x, off, 64);
        if (lane >= off) x += v2;
    }
    if (lane == 63) sh.wsA[wave] = x;
    if (t < MAXS) sh.povr[t] = -1;
    __syncthreads();
    int r = x - mcnt;
    #pragma unroll
    for (int w = 0; w < 4; ++w) if (w < wave) r += sh.wsA[w];
    #pragma unroll
    for (int k = 0; k < PERT; ++k) {
        if ((mbits >> k) & 1u) {
            if (r < MAXS) sh.pool[r] = s0 + k;
            ++r;
        }
    }
    int count = sh.wsA[0] + sh.wsA[1] + sh.wsA[2] + sh.wsA[3];
    __syncthreads();

    // ---- cold continuation (~3-4% of classes) ----
    for (int base = CHUNK; base < NTRAIN && count < MAXS; base += CHUNK) {
        const int s = base + t * PERT;
        unsigned mb = 0;
        int mc = 0;
        if (s < NTRAIN) {               // NTRAIN % PERT == 0: full vectors
            const float4* yp = (const float4*)(Y + s);
            mb = matchbits16(yp[0], yp[1], yp[2], yp[3], cf);
            for (int a2 = 0; a2 < nadd; ++a2) {
                unsigned rel = (unsigned)(sh.addl[a2] - s);
                if (rel < (unsigned)PERT) mb |= 1u << rel;
            }
            for (int r2 = 0; r2 < nrem; ++r2) {
                unsigned rel = (unsigned)(sh.reml[r2] - s);
                if (rel < (unsigned)PERT) mb &= ~(1u << rel);
            }
            mc = __popc(mb);
        }
        int xx = mc;
        #pragma unroll
        for (int off = 1; off < 64; off <<= 1) {
            int v2 = __shfl_up(xx, off, 64);
            if (lane >= off) xx += v2;
        }
        if (lane == 63) sh.wsA[wave] = xx;
        __syncthreads();
        int rr = count + (xx - mc);
        #pragma unroll
        for (int w = 0; w < 4; ++w) if (w < wave) rr += sh.wsA[w];
        #pragma unroll
        for (int k = 0; k < PERT; ++k) {
            if ((mb >> k) & 1u) {
                if (rr < MAXS) sh.pool[rr] = s + k;
                ++rr;
            }
        }
        count += sh.wsA[0] + sh.wsA[1] + sh.wsA[2] + sh.wsA[3];
        __syncthreads();
    }
    const int cnt = (count < MAXS) ? count : MAXS;

    // ---- resolve scatter overrides among pool entries; publish ----
    for (int k = 0; k < cnt; ++k)
        if (myi == sh.pool[k]) sh.povr[k] = t;    // at most one t matches
    __syncthreads();
    if (t < MAXS) {
        ws->pool[c][t] = (t < cnt) ? sh.pool[t] : 0;
        ws->povr[c][t] = (t < cnt) ? sh.povr[t] : -1;
    }
    if (t == 0) { ws->cnt[c] = cnt; ws->mult[c] = mult; ws->cntw[c] = mult * cnt; }
}

// ---- Phase A (regularizer block): partial sum of ||u|-1| over 1024 elems ----
__device__ __forceinline__ void phaseA_reg(
    int q, int t, const float* __restrict__ u, Ws* __restrict__ ws, ShMem& sh)
{
    const int lane = t & 63, wave = t >> 6;
    float4 v = ((const float4*)u)[q * 256 + t];
    float a = fabsf(fabsf(v.x) - 1.f) + fabsf(fabsf(v.y) - 1.f)
            + fabsf(fabsf(v.z) - 1.f) + fabsf(fabsf(v.w) - 1.f);
    #pragma unroll
    for (int off = 32; off; off >>= 1) a += __shfl_down(a, off, 64);
    if (lane == 0) sh.redf[wave] = a;
    __syncthreads();
    if (t == 0) ws->regp[q] = sh.redf[0] + sh.redf[1] + sh.redf[2] + sh.redf[3];
}

// ---- Phase B: pair loss of all 256 u-rows vs pool entries [4e, min(4e+4,cnt)) ----
__device__ __forceinline__ void phaseB(
    int j, int t, const float* __restrict__ u, const int* __restrict__ y,
    const float* __restrict__ U, Ws* __restrict__ ws, ShMem& sh)
{
    const int lane = t & 63, wave = t >> 6;
    const int c = j >> 3, e = j & 7;
    const int mult = ws->mult[c];
    if (mult == 0) {                    // block-uniform
        if (t == 0) ws->partial[j] = 0.f;
        return;
    }
    const int cnt = ws->cnt[c];
    const int p0 = e * EPB;
    const int pe = (p0 + EPB < cnt) ? p0 + EPB : cnt;
    {
        const int pp = t >> 6;          // local entry = wave id
        const int d  = t & 63;
        float v = 0.f;
        if (p0 + pp < pe) {
            const int ov = ws->povr[c][p0 + pp];
            const int bi = ws->pool[c][p0 + pp];
            v = (ov >= 0) ? u[ov * BIT + d] : U[bi * BIT + d];
        }
        sh.up[t] = v;
    }
    float4 ur[16];
    {
        const float4* urp = (const float4*)(u + t * BIT);
        #pragma unroll
        for (int q2 = 0; q2 < 16; ++q2) ur[q2] = urp[q2];
    }
    const bool same = (y[t] == c);
    __syncthreads();

    const int npool = pe - p0;
    float acc = 0.f;
    for (int pp = 0; pp < npool; ++pp) {
        const float4* up = (const float4*)(sh.up + pp * BIT);  // LDS broadcast
        float d0 = 0.f, d1 = 0.f, d2 = 0.f, d3 = 0.f;
        #pragma unroll
        for (int q2 = 0; q2 < 16; ++q2) {
            float4 v = up[q2];
            float a0 = ur[q2].x - v.x; d0 += a0 * a0;
            float a1 = ur[q2].y - v.y; d1 += a1 * a1;
            float a2 = ur[q2].z - v.z; d2 += a2 * a2;
            float a3 = ur[q2].w - v.w; d3 += a3 * a3;
        }
        const float dist = (d0 + d1) + (d2 + d3);
        acc += same ? dist : fmaxf(MVAL - dist, 0.f);
    }
    #pragma unroll
    for (int off = 32; off; off >>= 1) acc += __shfl_down(acc, off, 64);
    if (lane == 0) sh.redf[wave] = acc;
    __syncthreads();
    if (t == 0)
        ws->partial[j] = (float)mult * (sh.redf[0] + sh.redf[1] + sh.redf[2] + sh.redf[3]);
}

// ---- Phase C: reduce 800 partials + 16 reg partials + 100 cntw -> loss ----
__device__ __forceinline__ void phaseC(int t, Ws* __restrict__ ws,
                                       float* __restrict__ out, ShMem& sh)
{
    const int lane = t & 63, wave = t >> 6;
    float p = ws->partial[t] + ws->partial[t + 256] + ws->partial[t + 512];
    if (t < GRID_N - 768) p += ws->partial[t + 768];
    float a = (t < NREG) ? ws->regp[t] : 0.f;
    int  cc = (t < NCLS) ? ws->cntw[t] : 0;
    #pragma unroll
    for (int off = 32; off; off >>= 1) {
        p  += __shfl_down(p,  off, 64);
        a  += __shfl_down(a,  off, 64);
        cc += __shfl_down(cc, off, 64);
    }
    if (lane == 0) { sh.redf[wave] = p; sh.redg[wave] = a; sh.redi[wave] = cc; }
    __syncthreads();
    if (t == 0) {
        const float P = sh.redf[0] + sh.redf[1] + sh.redf[2] + sh.redf[3];
        const float A = sh.redg[0] + sh.redg[1] + sh.redg[2] + sh.redg[3];
        const int   S = sh.redi[0] + sh.redi[1] + sh.redi[2] + sh.redi[3];
        out[0] = 0.5f * P / (256.0f * (float)S) + ALPHA * (A * (1.0f / 16384.0f));
    }
}

// ================= single cooperative kernel =================
__global__ __launch_bounds__(256, 4) void dsh_coop_kernel(
    const float* __restrict__ u, const int* __restrict__ y,
    const int* __restrict__ ind, const float* __restrict__ U,
    const float* __restrict__ Y, Ws* __restrict__ ws, float* __restrict__ out)
{
    __shared__ ShMem sh;
    const int t = threadIdx.x;
    const int j = blockIdx.x;
    cg::grid_group grid = cg::this_grid();

    if (j < NCLS)             phaseA_class(j, t, y, ind, Y, ws, sh);
    else if (j < NCLS + NREG) phaseA_reg(j - NCLS, t, u, ws, sh);

    grid.sync();

    phaseB(j, t, u, y, U, ws, sh);

    grid.sync();

    if (j == 0) phaseC(t, ws, out, sh);
}

// ================= non-cooperative fallback (3 nodes) =================
__global__ __launch_bounds__(256) void dsh_phaseA_kernel(
    const float* __restrict__ u, const int* __restrict__ y,
    const int* __restrict__ ind, const float* __restrict__ Y,
    Ws* __restrict__ ws)
{
    __shared__ ShMem sh;
    const int j = blockIdx.x;
    if (j < NCLS) phaseA_class(j, threadIdx.x, y, ind, Y, ws, sh);
    else          phaseA_reg(j - NCLS, threadIdx.x, u, ws, sh);
}

__global__ __launch_bounds__(256) void dsh_phaseB_kernel(
    const float* __restrict__ u, const int* __restrict__ y,
    const float* __restrict__ U, Ws* __restrict__ ws)
{
    __shared__ ShMem sh;
    phaseB(blockIdx.x, threadIdx.x, u, y, U, ws, sh);
}

__global__ __launch_bounds__(256) void dsh_phaseC_kernel(
    Ws* __restrict__ ws, float* __restrict__ out)
{
    __shared__ ShMem sh;
    phaseC(threadIdx.x, ws, out, sh);
}

extern "C" void kernel_launch(void* const* d_in, const int* in_sizes, int n_in,
                              void* d_out, int out_size, void* d_ws, size_t ws_size,
                              hipStream_t stream) {
    const float* u   = (const float*)d_in[0];
    const int*   y   = (const int*)d_in[1];
    const int*   ind = (const int*)d_in[2];
    const float* U   = (const float*)d_in[3];
    const float* Y   = (const float*)d_in[4];
    float* out = (float*)d_out;
    Ws*    ws  = (Ws*)d_ws;

    void* args[] = { (void*)&u, (void*)&y, (void*)&ind, (void*)&U, (void*)&Y,
                     (void*)&ws, (void*)&out };
    hipError_t err = hipLaunchCooperativeKernel(
        (const void*)dsh_coop_kernel, dim3(GRID_N), dim3(256), args, 0, stream);
    if (err != hipSuccess) {
        // fallback: same device code, three plain graph nodes
        dsh_phaseA_kernel<<<dim3(NCLS + NREG), dim3(256), 0, stream>>>(u, y, ind, Y, ws);
        dsh_phaseB_kernel<<<dim3(GRID_N), dim3(256), 0, stream>>>(u, y, U, ws);
        dsh_phaseC_kernel<<<dim3(1), dim3(256), 0, stream>>>(ws, out);
    }
}

// Round 8
// 31.826 us; speedup vs baseline: 6.4965x; 6.4965x over previous
//
#include <hip/hip_runtime.h>

#define NTRAIN 200000
#define NB     256
#define BIT    64
#define MAXS   30
#define NCLS   100
#define EPB    4            // pool entries per block
#define CHUNK  4096
#define PERT   16
#define NCLSB  (NCLS * 8)   // 800 pair blocks
#define MVAL   128.0f
#define ALPHA  0.01f

// ---- workspace layout (byte offsets) ----
// partial[800] @ 0, cntw[100] @ 4096, oct[8] @ 8192, root @ 8224, regsum @ 8240

// Node 1: single block. Resets arrival counters for this launch (replacing a
// costly memset node) and computes the regularizer sum over u (64 KB).
__global__ __launch_bounds__(256) void dsh_prep_kernel(
    const float* __restrict__ u, int* __restrict__ oct, int* __restrict__ root,
    float* __restrict__ regsum)
{
    const int t = threadIdx.x;
    const int lane = t & 63, wave = t >> 6;
    __shared__ float redf[4];

    if (t < 8) oct[t] = 0;
    if (t == 8) *root = 0;

    float a = 0.f;
    #pragma unroll
    for (int k = 0; k < 16; ++k) {      // 16384 floats, float4-coalesced
        float4 v = ((const float4*)u)[t + 256 * k];
        a += fabsf(fabsf(v.x) - 1.f) + fabsf(fabsf(v.y) - 1.f)
           + fabsf(fabsf(v.z) - 1.f) + fabsf(fabsf(v.w) - 1.f);
    }
    #pragma unroll
    for (int off = 32; off; off >>= 1) a += __shfl_down(a, off, 64);
    if (lane == 0) redf[wave] = a;
    __syncthreads();
    if (t == 0) *regsum = redf[0] + redf[1] + redf[2] + redf[3];
}

// Node 2: 800 blocks, j = (class c = j>>3, entry-chunk e = j&7). Round-6 body
// + coherent-store/arrival-tree epilogue; global-last block writes the loss.
__global__ __launch_bounds__(256) void dsh_main_kernel(
    const float* __restrict__ u, const int* __restrict__ y,
    const int* __restrict__ ind, const float* __restrict__ U,
    const float* __restrict__ Y,
    float* __restrict__ partial, int* __restrict__ cntw,
    int* __restrict__ oct, int* __restrict__ root,
    const float* __restrict__ regsum, float* __restrict__ out)
{
    __shared__ int   addl[NB];
    __shared__ int   reml[NB];
    __shared__ float up_l[EPB * BIT];
    __shared__ int   pool[MAXS];
    __shared__ int   povr[EPB];
    __shared__ int   wsA[4], wsB[4], wsC[4];
    __shared__ float redf[4], redg[4];
    __shared__ int   redi[4];
    __shared__ int   lastflag;

    const int t    = threadIdx.x;
    const int j    = blockIdx.x;
    const int lane = t & 63;
    const int wave = t >> 6;

    const int c = j >> 3;
    const int e = j & 7;
    const float cf = (float)c;

    float myPair = 0.f;
    int   myCntW = (e == 0) ? 0 : -1;

    // ---- front-end loads (one vmcnt wall) ----
    const int myi = ind[t];
    const int myy = y[t];
    const int s0  = t * PERT;
    float4 yv0, yv1, yv2, yv3;
    {
        const float4* yp = (const float4*)(Y + s0);
        yv0 = yp[0]; yv1 = yp[1]; yv2 = yp[2]; yv3 = yp[3];
    }
    const float ybank = Y[myi];

    // ---- ballots: multiplicity + scatter-correction lists ----
    const bool ismem = (myy == c);
    const bool fneg  = ismem && (ybank != cf);
    const bool fpos  = (!ismem) && (ybank == cf);
    unsigned long long balm = __ballot(ismem);
    unsigned long long bala = __ballot(fneg);
    unsigned long long balr = __ballot(fpos);
    if (lane == 0) {
        wsA[wave] = (int)__popcll(balm);
        wsB[wave] = (int)__popcll(bala);
        wsC[wave] = (int)__popcll(balr);
    }
    __syncthreads();
    const int mult = wsA[0] + wsA[1] + wsA[2] + wsA[3];

    if (mult > 0) {                     // block-uniform
        const int nadd = wsB[0] + wsB[1] + wsB[2] + wsB[3];
        const int nrem = wsC[0] + wsC[1] + wsC[2] + wsC[3];
        int pa = 0, pr = 0;
        #pragma unroll
        for (int w = 0; w < 4; ++w) if (w < wave) { pa += wsB[w]; pr += wsC[w]; }
        const unsigned long long lm = (1ull << lane) - 1ull;
        if (fneg) addl[pa + (int)__popcll(bala & lm)] = myi;
        if (fpos) reml[pr + (int)__popcll(balr & lm)] = myi;
        __syncthreads();

        // ---- scan chunk 0 (prefetched) ----
        unsigned mbits = 0;
        if (yv0.x == cf) mbits |= 1u << 0;
        if (yv0.y == cf) mbits |= 1u << 1;
        if (yv0.z == cf) mbits |= 1u << 2;
        if (yv0.w == cf) mbits |= 1u << 3;
        if (yv1.x == cf) mbits |= 1u << 4;
        if (yv1.y == cf) mbits |= 1u << 5;
        if (yv1.z == cf) mbits |= 1u << 6;
        if (yv1.w == cf) mbits |= 1u << 7;
        if (yv2.x == cf) mbits |= 1u << 8;
        if (yv2.y == cf) mbits |= 1u << 9;
        if (yv2.z == cf) mbits |= 1u << 10;
        if (yv2.w == cf) mbits |= 1u << 11;
        if (yv3.x == cf) mbits |= 1u << 12;
        if (yv3.y == cf) mbits |= 1u << 13;
        if (yv3.z == cf) mbits |= 1u << 14;
        if (yv3.w == cf) mbits |= 1u << 15;
        for (int a2 = 0; a2 < nadd; ++a2) {
            unsigned rel = (unsigned)(addl[a2] - s0);
            if (rel < (unsigned)PERT) mbits |= 1u << rel;
        }
        for (int r2 = 0; r2 < nrem; ++r2) {
            unsigned rel = (unsigned)(reml[r2] - s0);
            if (rel < (unsigned)PERT) mbits &= ~(1u << rel);
        }
        const int mcnt = __popc(mbits);

        int x = mcnt;
        #pragma unroll
        for (int off = 1; off < 64; off <<= 1) {
            int v2 = __shfl_up(x, off, 64);
            if (lane >= off) x += v2;
        }
        if (lane == 63) wsA[wave] = x;
        if (t < EPB) povr[t] = -1;
        __syncthreads();
        int r = x - mcnt;
        #pragma unroll
        for (int w = 0; w < 4; ++w) if (w < wave) r += wsA[w];
        #pragma unroll
        for (int k = 0; k < PERT; ++k) {
            if ((mbits >> k) & 1u) {
                if (r < MAXS) pool[r] = s0 + k;
                ++r;
            }
        }
        int count = wsA[0] + wsA[1] + wsA[2] + wsA[3];
        __syncthreads();

        // ---- cold continuation (~3-4% of classes) ----
        for (int base = CHUNK; base < NTRAIN && count < MAXS; base += CHUNK) {
            const int s = base + t * PERT;
            unsigned mb = 0;
            int mc = 0;
            if (s < NTRAIN) {
                const float4* yp = (const float4*)(Y + s);
                float4 a0 = yp[0], a1 = yp[1], a2v = yp[2], a3 = yp[3];
                if (a0.x == cf) mb |= 1u << 0;
                if (a0.y == cf) mb |= 1u << 1;
                if (a0.z == cf) mb |= 1u << 2;
                if (a0.w == cf) mb |= 1u << 3;
                if (a1.x == cf) mb |= 1u << 4;
                if (a1.y == cf) mb |= 1u << 5;
                if (a1.z == cf) mb |= 1u << 6;
                if (a1.w == cf) mb |= 1u << 7;
                if (a2v.x == cf) mb |= 1u << 8;
                if (a2v.y == cf) mb |= 1u << 9;
                if (a2v.z == cf) mb |= 1u << 10;
                if (a2v.w == cf) mb |= 1u << 11;
                if (a3.x == cf) mb |= 1u << 12;
                if (a3.y == cf) mb |= 1u << 13;
                if (a3.z == cf) mb |= 1u << 14;
                if (a3.w == cf) mb |= 1u << 15;
                for (int a2 = 0; a2 < nadd; ++a2) {
                    unsigned rel = (unsigned)(addl[a2] - s);
                    if (rel < (unsigned)PERT) mb |= 1u << rel;
                }
                for (int r2 = 0; r2 < nrem; ++r2) {
                    unsigned rel = (unsigned)(reml[r2] - s);
                    if (rel < (unsigned)PERT) mb &= ~(1u << rel);
                }
                mc = __popc(mb);
            }
            int xx = mc;
            #pragma unroll
            for (int off = 1; off < 64; off <<= 1) {
                int v2 = __shfl_up(xx, off, 64);
                if (lane >= off) xx += v2;
            }
            if (lane == 63) wsA[wave] = xx;
            __syncthreads();
            int rr = count + (xx - mc);
            #pragma unroll
            for (int w = 0; w < 4; ++w) if (w < wave) rr += wsA[w];
            #pragma unroll
            for (int k = 0; k < PERT; ++k) {
                if ((mb >> k) & 1u) {
                    if (rr < MAXS) pool[rr] = s + k;
                    ++rr;
                }
            }
            count += wsA[0] + wsA[1] + wsA[2] + wsA[3];
            __syncthreads();
        }
        const int cnt = (count < MAXS) ? count : MAXS;

        // ---- overrides among this block's pool entries ----
        const int p0 = e * EPB;
        const int pe = (p0 + EPB < cnt) ? p0 + EPB : cnt;
        for (int k2 = p0; k2 < pe; ++k2)
            if (myi == pool[k2]) povr[k2 - p0] = t;
        __syncthreads();

        // ---- u-row prefetch + pool gather ----
        float4 ur[16];
        {
            const float4* urp = (const float4*)(u + t * BIT);
            #pragma unroll
            for (int q2 = 0; q2 < 16; ++q2) ur[q2] = urp[q2];
        }
        {
            const int pp = t >> 6;
            const int d  = t & 63;
            float v = 0.f;
            if (p0 + pp < pe) {
                const int ov = povr[pp];
                v = (ov >= 0) ? u[ov * BIT + d] : U[pool[p0 + pp] * BIT + d];
            }
            up_l[t] = v;
        }
        __syncthreads();

        // ---- pair loss ----
        const bool same = (myy == c);
        const int npool = pe - p0;
        float acc = 0.f;
        for (int pp = 0; pp < npool; ++pp) {
            const float4* up = (const float4*)(up_l + pp * BIT);
            float d0 = 0.f, d1 = 0.f, d2 = 0.f, d3 = 0.f;
            #pragma unroll
            for (int q2 = 0; q2 < 16; ++q2) {
                float4 v = up[q2];
                float a0 = ur[q2].x - v.x; d0 += a0 * a0;
                float a1 = ur[q2].y - v.y; d1 += a1 * a1;
                float a2 = ur[q2].z - v.z; d2 += a2 * a2;
                float a3 = ur[q2].w - v.w; d3 += a3 * a3;
            }
            const float dist = (d0 + d1) + (d2 + d3);
            acc += same ? dist : fmaxf(MVAL - dist, 0.f);
        }
        #pragma unroll
        for (int off = 32; off; off >>= 1) acc += __shfl_down(acc, off, 64);
        if (lane == 0) redf[wave] = acc;
        __syncthreads();
        if (t == 0) {
            myPair = (float)mult * (redf[0] + redf[1] + redf[2] + redf[3]);
            if (e == 0) myCntW = mult * cnt;
        }
    }

    // ---- epilogue: coherent publish + two-level arrival tree ----
    if (t == 0) {
        __hip_atomic_store(&partial[j], myPair, __ATOMIC_RELAXED,
                           __HIP_MEMORY_SCOPE_AGENT);
        if (myCntW >= 0)
            __hip_atomic_store(&cntw[c], myCntW, __ATOMIC_RELAXED,
                               __HIP_MEMORY_SCOPE_AGENT);
        asm volatile("s_waitcnt vmcnt(0)" ::: "memory");   // stores at coherent pt
        int isLast = 0;
        int oo = __hip_atomic_fetch_add(&oct[j / 100], 1, __ATOMIC_RELAXED,
                                        __HIP_MEMORY_SCOPE_AGENT);
        if (oo == 99) {                 // subgroup-last: its 100 blocks all published
            int ro = __hip_atomic_fetch_add(root, 1, __ATOMIC_RELAXED,
                                            __HIP_MEMORY_SCOPE_AGENT);
            isLast = (ro == 7);         // global-last: all 800 published
        }
        lastflag = isLast;
    }
    __syncthreads();
    if (!lastflag) return;

    // ---- global-last block: reduce 800 partials + 100 cntw -> loss ----
    float p = __hip_atomic_fetch_add(&partial[t], 0.f, __ATOMIC_RELAXED,
                                     __HIP_MEMORY_SCOPE_AGENT)
            + __hip_atomic_fetch_add(&partial[t + 256], 0.f, __ATOMIC_RELAXED,
                                     __HIP_MEMORY_SCOPE_AGENT)
            + __hip_atomic_fetch_add(&partial[t + 512], 0.f, __ATOMIC_RELAXED,
                                     __HIP_MEMORY_SCOPE_AGENT);
    if (t < NCLSB - 768)
        p += __hip_atomic_fetch_add(&partial[t + 768], 0.f, __ATOMIC_RELAXED,
                                    __HIP_MEMORY_SCOPE_AGENT);
    int cc = (t < NCLS)
           ? __hip_atomic_fetch_add(&cntw[t], 0, __ATOMIC_RELAXED,
                                    __HIP_MEMORY_SCOPE_AGENT)
           : 0;
    #pragma unroll
    for (int off = 32; off; off >>= 1) {
        p  += __shfl_down(p,  off, 64);
        cc += __shfl_down(cc, off, 64);
    }
    if (lane == 0) { redg[wave] = p; redi[wave] = cc; }
    __syncthreads();
    if (t == 0) {
        const float P = redg[0] + redg[1] + redg[2] + redg[3];
        const int   S = redi[0] + redi[1] + redi[2] + redi[3];
        const float A = *regsum;        // node-1 output, node-boundary coherent
        out[0] = 0.5f * P / (256.0f * (float)S)
               + ALPHA * (A * (1.0f / 16384.0f));
    }
}

extern "C" void kernel_launch(void* const* d_in, const int* in_sizes, int n_in,
                              void* d_out, int out_size, void* d_ws, size_t ws_size,
                              hipStream_t stream) {
    const float* u   = (const float*)d_in[0];
    const int*   y   = (const int*)d_in[1];
    const int*   ind = (const int*)d_in[2];
    const float* U   = (const float*)d_in[3];
    const float* Y   = (const float*)d_in[4];
    float* out = (float*)d_out;

    float* partial = (float*)d_ws;                       // [800]
    int*   cntw    = (int*)((char*)d_ws + 4096);         // [100]
    int*   oct     = (int*)((char*)d_ws + 8192);         // [8]
    int*   root    = (int*)((char*)d_ws + 8224);         // [1]
    float* regsum  = (float*)((char*)d_ws + 8240);       // [1]

    dsh_prep_kernel<<<dim3(1), dim3(256), 0, stream>>>(u, oct, root, regsum);
    dsh_main_kernel<<<dim3(NCLSB), dim3(256), 0, stream>>>(
        u, y, ind, U, Y, partial, cntw, oct, root, regsum, out);
}

// Round 9
// 23.426 us; speedup vs baseline: 8.8257x; 1.3585x over previous
//
#include <hip/hip_runtime.h>

#define NTRAIN 200000
#define NB     256
#define BIT    64
#define MAXS   30
#define NCLS   100
#define CHUNK  4096
#define PERT   16
#define NREG   16
#define MVAL   128.0f
#define ALPHA  0.01f

#define NBIN   128
#define BSTR   16           // bin stride in floats (64 B -> own cache line)
#define PAIRB  (NCLS * 32)  // 3200 pair blocks: class x 8 entry-chunks x 4 row-quarters

// ---- workspace layout ----
struct Ws {
    int   pool[NCLS][32];
    int   povr[NCLS][32];
    int   cnt[NCLS];
    int   mult[NCLS];
    int   cntw[NCLS];
    float regp[NREG];
    float bins[NBIN * BSTR];
};

// ================= node 1: class scans + regularizer + bin reset =================
__global__ __launch_bounds__(256) void dsh_scan_kernel(
    const float* __restrict__ u, const int* __restrict__ y,
    const int* __restrict__ ind, const float* __restrict__ Y,
    Ws* __restrict__ ws)
{
    __shared__ int   addl[NB];
    __shared__ int   reml[NB];
    __shared__ int   pool[MAXS];
    __shared__ int   povr[MAXS];
    __shared__ int   wsA[4], wsB[4], wsC[4];
    __shared__ float redf[4];

    const int t    = threadIdx.x;
    const int j    = blockIdx.x;
    const int lane = t & 63;
    const int wave = t >> 6;

    if (j >= NCLS + NREG) {             // ---- bin reset block ----
        if (t < NBIN) ws->bins[t * BSTR] = 0.f;
        return;
    }
    if (j >= NCLS) {                    // ---- regularizer blocks ----
        const int q = j - NCLS;
        float4 v = ((const float4*)u)[q * 256 + t];
        float a = fabsf(fabsf(v.x) - 1.f) + fabsf(fabsf(v.y) - 1.f)
                + fabsf(fabsf(v.z) - 1.f) + fabsf(fabsf(v.w) - 1.f);
        #pragma unroll
        for (int off = 32; off; off >>= 1) a += __shfl_down(a, off, 64);
        if (lane == 0) redf[wave] = a;
        __syncthreads();
        if (t == 0) ws->regp[q] = redf[0] + redf[1] + redf[2] + redf[3];
        return;
    }

    // ---- class block c = j ----
    const int c = j;
    const float cf = (float)c;

    const int myi = ind[t];
    const int myy = y[t];
    const int s0  = t * PERT;
    float4 yv0, yv1, yv2, yv3;          // Y chunk 0, prefetched
    {
        const float4* yp = (const float4*)(Y + s0);
        yv0 = yp[0]; yv1 = yp[1]; yv2 = yp[2]; yv3 = yp[3];
    }
    const float ybank = Y[myi];

    const bool ismem = (myy == c);
    const bool fneg  = ismem && (ybank != cf);    // becomes class c
    const bool fpos  = (!ismem) && (ybank == cf); // stops being class c
    unsigned long long balm = __ballot(ismem);
    unsigned long long bala = __ballot(fneg);
    unsigned long long balr = __ballot(fpos);
    if (lane == 0) {
        wsA[wave] = (int)__popcll(balm);
        wsB[wave] = (int)__popcll(bala);
        wsC[wave] = (int)__popcll(balr);
    }
    __syncthreads();
    const int mult = wsA[0] + wsA[1] + wsA[2] + wsA[3];
    if (mult == 0) {                    // block-uniform
        if (t == 0) { ws->cnt[c] = 0; ws->mult[c] = 0; ws->cntw[c] = 0; }
        return;
    }
    const int nadd = wsB[0] + wsB[1] + wsB[2] + wsB[3];
    const int nrem = wsC[0] + wsC[1] + wsC[2] + wsC[3];
    int pa = 0, pr = 0;
    #pragma unroll
    for (int w = 0; w < 4; ++w) if (w < wave) { pa += wsB[w]; pr += wsC[w]; }
    const unsigned long long lm = (1ull << lane) - 1ull;
    if (fneg) addl[pa + (int)__popcll(bala & lm)] = myi;
    if (fpos) reml[pr + (int)__popcll(balr & lm)] = myi;
    __syncthreads();

    // ---- scan chunk 0 (prefetched) ----
    unsigned mbits = 0;
    if (yv0.x == cf) mbits |= 1u << 0;
    if (yv0.y == cf) mbits |= 1u << 1;
    if (yv0.z == cf) mbits |= 1u << 2;
    if (yv0.w == cf) mbits |= 1u << 3;
    if (yv1.x == cf) mbits |= 1u << 4;
    if (yv1.y == cf) mbits |= 1u << 5;
    if (yv1.z == cf) mbits |= 1u << 6;
    if (yv1.w == cf) mbits |= 1u << 7;
    if (yv2.x == cf) mbits |= 1u << 8;
    if (yv2.y == cf) mbits |= 1u << 9;
    if (yv2.z == cf) mbits |= 1u << 10;
    if (yv2.w == cf) mbits |= 1u << 11;
    if (yv3.x == cf) mbits |= 1u << 12;
    if (yv3.y == cf) mbits |= 1u << 13;
    if (yv3.z == cf) mbits |= 1u << 14;
    if (yv3.w == cf) mbits |= 1u << 15;
    for (int a2 = 0; a2 < nadd; ++a2) {
        unsigned rel = (unsigned)(addl[a2] - s0);
        if (rel < (unsigned)PERT) mbits |= 1u << rel;
    }
    for (int r2 = 0; r2 < nrem; ++r2) {
        unsigned rel = (unsigned)(reml[r2] - s0);
        if (rel < (unsigned)PERT) mbits &= ~(1u << rel);
    }
    const int mcnt = __popc(mbits);

    int x = mcnt;                       // ordered inclusive wave scan
    #pragma unroll
    for (int off = 1; off < 64; off <<= 1) {
        int v2 = __shfl_up(x, off, 64);
        if (lane >= off) x += v2;
    }
    if (lane == 63) wsA[wave] = x;
    if (t < MAXS) povr[t] = -1;
    __syncthreads();
    int r = x - mcnt;
    #pragma unroll
    for (int w = 0; w < 4; ++w) if (w < wave) r += wsA[w];
    #pragma unroll
    for (int k = 0; k < PERT; ++k) {
        if ((mbits >> k) & 1u) {
            if (r < MAXS) pool[r] = s0 + k;
            ++r;
        }
    }
    int count = wsA[0] + wsA[1] + wsA[2] + wsA[3];
    __syncthreads();

    // ---- cold continuation (~3-4% of classes) ----
    for (int base = CHUNK; base < NTRAIN && count < MAXS; base += CHUNK) {
        const int s = base + t * PERT;
        unsigned mb = 0;
        int mc = 0;
        if (s < NTRAIN) {               // NTRAIN % PERT == 0: full vectors
            const float4* yp = (const float4*)(Y + s);
            float4 a0 = yp[0], a1 = yp[1], a2v = yp[2], a3 = yp[3];
            if (a0.x == cf) mb |= 1u << 0;
            if (a0.y == cf) mb |= 1u << 1;
            if (a0.z == cf) mb |= 1u << 2;
            if (a0.w == cf) mb |= 1u << 3;
            if (a1.x == cf) mb |= 1u << 4;
            if (a1.y == cf) mb |= 1u << 5;
            if (a1.z == cf) mb |= 1u << 6;
            if (a1.w == cf) mb |= 1u << 7;
            if (a2v.x == cf) mb |= 1u << 8;
            if (a2v.y == cf) mb |= 1u << 9;
            if (a2v.z == cf) mb |= 1u << 10;
            if (a2v.w == cf) mb |= 1u << 11;
            if (a3.x == cf) mb |= 1u << 12;
            if (a3.y == cf) mb |= 1u << 13;
            if (a3.z == cf) mb |= 1u << 14;
            if (a3.w == cf) mb |= 1u << 15;
            for (int a2 = 0; a2 < nadd; ++a2) {
                unsigned rel = (unsigned)(addl[a2] - s);
                if (rel < (unsigned)PERT) mb |= 1u << rel;
            }
            for (int r2 = 0; r2 < nrem; ++r2) {
                unsigned rel = (unsigned)(reml[r2] - s);
                if (rel < (unsigned)PERT) mb &= ~(1u << rel);
            }
            mc = __popc(mb);
        }
        int xx = mc;
        #pragma unroll
        for (int off = 1; off < 64; off <<= 1) {
            int v2 = __shfl_up(xx, off, 64);
            if (lane >= off) xx += v2;
        }
        if (lane == 63) wsA[wave] = xx;
        __syncthreads();
        int rr = count + (xx - mc);
        #pragma unroll
        for (int w = 0; w < 4; ++w) if (w < wave) rr += wsA[w];
        #pragma unroll
        for (int k = 0; k < PERT; ++k) {
            if ((mb >> k) & 1u) {
                if (rr < MAXS) pool[rr] = s + k;
                ++rr;
            }
        }
        count += wsA[0] + wsA[1] + wsA[2] + wsA[3];
        __syncthreads();
    }
    const int cnt = (count < MAXS) ? count : MAXS;

    // ---- resolve scatter overrides among all pool entries; publish ----
    for (int k = 0; k < cnt; ++k)
        if (myi == pool[k]) povr[k] = t;          // at most one t matches
    __syncthreads();
    if (t < MAXS) {
        ws->pool[c][t] = (t < cnt) ? pool[t] : 0;
        ws->povr[c][t] = (t < cnt) ? povr[t] : -1;
    }
    if (t == 0) {
        ws->cnt[c]  = cnt;
        ws->mult[c] = mult;
        ws->cntw[c] = mult * cnt;
    }
}

// ================= node 2: wave-sized pair blocks (no barriers, no LDS) =====
// block j: class c = j>>5, entry-chunk e = (j>>2)&7, row-quarter rq = j&3.
__global__ __launch_bounds__(64) void dsh_pair_kernel(
    const float* __restrict__ u, const int* __restrict__ y,
    const float* __restrict__ U, Ws* __restrict__ ws)
{
    const int t  = threadIdx.x;         // lane 0..63
    const int j  = blockIdx.x;
    const int c  = j >> 5;
    const int e  = (j >> 2) & 7;
    const int rq = j & 3;

    const int mult = ws->mult[c];
    if (mult == 0) return;
    const int cnt = ws->cnt[c];
    const int p0  = e * 4;
    if (p0 >= cnt) return;
    const int pe  = (p0 + 4 < cnt) ? p0 + 4 : cnt;

    const int i = rq * 64 + t;          // batch row
    const bool same = (y[i] == c);

    float4 ur[16];
    {
        const float4* urp = (const float4*)(u + i * BIT);
        #pragma unroll
        for (int q = 0; q < 16; ++q) ur[q] = urp[q];
    }

    float acc = 0.f;
    for (int p = p0; p < pe; ++p) {
        const int ov = ws->povr[c][p];  // uniform scalar loads
        const int bi = ws->pool[c][p];
        const float4* rp = (ov >= 0) ? (const float4*)(u + ov * BIT)
                                     : (const float4*)(U + bi * BIT);
        float d0 = 0.f, d1 = 0.f, d2 = 0.f, d3 = 0.f;
        #pragma unroll
        for (int q = 0; q < 16; ++q) {
            float4 v = rp[q];           // wave-uniform broadcast load
            float a0 = ur[q].x - v.x; d0 += a0 * a0;
            float a1 = ur[q].y - v.y; d1 += a1 * a1;
            float a2 = ur[q].z - v.z; d2 += a2 * a2;
            float a3 = ur[q].w - v.w; d3 += a3 * a3;
        }
        const float dist = (d0 + d1) + (d2 + d3);
        acc += same ? dist : fmaxf(MVAL - dist, 0.f);
    }

    #pragma unroll
    for (int off = 32; off; off >>= 1) acc += __shfl_down(acc, off, 64);
    if (t == 0)
        atomicAdd(&ws->bins[(j & (NBIN - 1)) * BSTR], (float)mult * acc);
}

// ================= node 3: tiny final reduction =================
__global__ __launch_bounds__(256) void dsh_reduce_kernel(
    Ws* __restrict__ ws, float* __restrict__ out)
{
    const int t = threadIdx.x;
    const int lane = t & 63, wave = t >> 6;
    __shared__ float redp[4], reda[4];
    __shared__ int   redc[4];

    float p = (t < NBIN) ? ws->bins[t * BSTR] : 0.f;
    float a = (t < NREG) ? ws->regp[t] : 0.f;
    int  cc = (t < NCLS) ? ws->cntw[t] : 0;
    #pragma unroll
    for (int off = 32; off; off >>= 1) {
        p  += __shfl_down(p,  off, 64);
        a  += __shfl_down(a,  off, 64);
        cc += __shfl_down(cc, off, 64);
    }
    if (lane == 0) { redp[wave] = p; reda[wave] = a; redc[wave] = cc; }
    __syncthreads();
    if (t == 0) {
        const float P = redp[0] + redp[1] + redp[2] + redp[3];
        const float A = reda[0] + reda[1] + reda[2] + reda[3];
        const int   S = redc[0] + redc[1] + redc[2] + redc[3];
        out[0] = 0.5f * P / (256.0f * (float)S)
               + ALPHA * (A * (1.0f / 16384.0f));
    }
}

extern "C" void kernel_launch(void* const* d_in, const int* in_sizes, int n_in,
                              void* d_out, int out_size, void* d_ws, size_t ws_size,
                              hipStream_t stream) {
    const float* u   = (const float*)d_in[0];
    const int*   y   = (const int*)d_in[1];
    const int*   ind = (const int*)d_in[2];
    const float* U   = (const float*)d_in[3];
    const float* Y   = (const float*)d_in[4];
    float* out = (float*)d_out;
    Ws*    ws  = (Ws*)d_ws;

    dsh_scan_kernel<<<dim3(NCLS + NREG + 1), dim3(256), 0, stream>>>(u, y, ind, Y, ws);
    dsh_pair_kernel<<<dim3(PAIRB), dim3(64), 0, stream>>>(u, y, U, ws);
    dsh_reduce_kernel<<<dim3(1), dim3(256), 0, stream>>>(ws, out);
}

// Round 10
// 22.245 us; speedup vs baseline: 9.2943x; 1.0531x over previous
//
#include <hip/hip_runtime.h>

#define NTRAIN 200000
#define NB     256
#define BIT    64
#define MAXS   30
#define NCLS   100
#define ESPL   8            // entry-chunks per class
#define EPB    4            // pool entries per block (8*4 >= 30)
#define CHUNK  4096
#define PERT   16
#define NREG   16           // regularizer blocks (1024 u-elems each)
#define MVAL   128.0f
#define ALPHA  0.01f

// Blocks [0, 800): (class c, entry-chunk e) — scan for class pool, compute
// pair loss of all 256 rows vs pool entries [4e, min(4e+4, cnt)), x mult.
// Blocks [800, 816): partial sums of | |u| - 1 |.
__global__ __launch_bounds__(256) void dsh_main_kernel(
    const float* __restrict__ u, const int* __restrict__ y,
    const int* __restrict__ ind, const float* __restrict__ U,
    const float* __restrict__ Y,
    float* __restrict__ partial, int* __restrict__ cntw)
{
    __shared__ int   ovrT[CHUNK];       // transposed [16][256] override map
    __shared__ float up_l[EPB * BIT];
    __shared__ int   ind_l[NB];
    __shared__ int   y_l[NB];
    __shared__ int   pool[MAXS];
    __shared__ int   povr[EPB];
    __shared__ int   wsum[4];
    __shared__ float red[4];

    const int t    = threadIdx.x;
    const int j    = blockIdx.x;
    const int lane = t & 63;
    const int wave = t >> 6;

    if (j >= NCLS * ESPL) {             // ---- regularizer partials ----
        const int q = j - NCLS * ESPL;
        float4 v = ((const float4*)u)[q * 256 + t];
        float a = fabsf(fabsf(v.x) - 1.f) + fabsf(fabsf(v.y) - 1.f)
                + fabsf(fabsf(v.z) - 1.f) + fabsf(fabsf(v.w) - 1.f);
        #pragma unroll
        for (int off = 32; off; off >>= 1) a += __shfl_down(a, off, 64);
        if (lane == 0) red[wave] = a;
        __syncthreads();
        if (t == 0) partial[j] = red[0] + red[1] + red[2] + red[3];
        return;
    }

    const int c = j >> 3;               // class
    const int e = j & 7;                // entry-chunk

    ind_l[t] = ind[t];
    y_l[t]   = y[t];
    __syncthreads();

    // multiplicity of class c in the batch
    unsigned long long bal = __ballot(y_l[t] == c);
    if (lane == 0) wsum[wave] = (int)__popcll(bal);
    __syncthreads();
    const int mult = wsum[0] + wsum[1] + wsum[2] + wsum[3];
    if (mult == 0) {
        if (t == 0) { partial[j] = 0.f; if (e == 0) cntw[c] = 0; }
        return;
    }
    __syncthreads();                    // wsum reused below

    const float cf = (float)c;

    // ---- scan: first MAXS ascending matches over virtually-scattered bank ----
    int count = 0;
    for (int base = 0; base < NTRAIN && count < MAXS; base += CHUNK) {
        const int s = base + t * PERT;
        float yf[PERT];
        if (s < NTRAIN) {               // issue Y loads before LDS work
            #pragma unroll
            for (int q2 = 0; q2 < 4; ++q2)
                ((float4*)yf)[q2] = ((const float4*)(Y + s))[q2];
        }
        #pragma unroll
        for (int k2 = 0; k2 < 4; ++k2)
            ((int4*)ovrT)[t + 256 * k2] = make_int4(-1, -1, -1, -1);
        __syncthreads();
        unsigned rel = (unsigned)(ind_l[t] - base);
        if (rel < (unsigned)CHUNK)
            ovrT[(rel & 15) * 256 + (rel >> 4)] = t;   // ind distinct
        __syncthreads();

        unsigned mbits = 0; int mcnt = 0;
        if (s < NTRAIN) {
            #pragma unroll
            for (int k2 = 0; k2 < PERT; ++k2) {
                int o = ovrT[k2 * 256 + t];            // lane-stride-1: no conflict
                bool m = (o >= 0) ? (y_l[o] == c) : (yf[k2] == cf);
                if (m) { mbits |= (1u << k2); ++mcnt; }
            }
        }
        // ordered inclusive block scan of mcnt
        int x = mcnt;
        #pragma unroll
        for (int off = 1; off < 64; off <<= 1) {
            int v = __shfl_up(x, off, 64);
            if (lane >= off) x += v;
        }
        if (lane == 63) wsum[wave] = x;
        __syncthreads();
        int wpre = 0;
        #pragma unroll
        for (int w = 0; w < 4; ++w) if (w < wave) wpre += wsum[w];
        int r = count + wpre + (x - mcnt);             // exclusive global rank
        #pragma unroll
        for (int k2 = 0; k2 < PERT; ++k2) {
            if ((mbits >> k2) & 1u) {
                if (r < MAXS) pool[r] = s + k2;
                ++r;
            }
        }
        count += wsum[0] + wsum[1] + wsum[2] + wsum[3];
        __syncthreads();
    }
    const int cnt = (count < MAXS) ? count : MAXS;

    // ---- this block's entries: overrides + gather ----
    const int p0 = e * EPB;
    const int pe = (p0 + EPB < cnt) ? p0 + EPB : cnt;
    if (t < EPB) povr[t] = -1;
    __syncthreads();
    for (int k2 = p0; k2 < pe; ++k2)
        if (ind_l[t] == pool[k2]) povr[k2 - p0] = t;   // at most one t
    __syncthreads();
    {
        const int pp = t >> 6;          // local entry 0..3
        const int d  = t & 63;
        float v = 0.f;
        if (p0 + pp < pe) {
            const int ov = povr[pp];
            v = (ov >= 0) ? u[ov * BIT + d] : U[pool[p0 + pp] * BIT + d];
        }
        up_l[t] = v;
    }
    __syncthreads();

    // ---- pair loss: thread t = batch row t vs entries [p0, pe) ----
    float4 ur[16];
    {
        const float4* urp = (const float4*)(u + t * BIT);
        #pragma unroll
        for (int q2 = 0; q2 < 16; ++q2) ur[q2] = urp[q2];
    }
    const bool same = (y_l[t] == c);
    const int npool = pe - p0;
    float acc = 0.f;
    for (int pp = 0; pp < npool; ++pp) {
        const float4* up = (const float4*)(up_l + pp * BIT);
        float d0 = 0.f, d1 = 0.f, d2 = 0.f, d3 = 0.f;
        #pragma unroll
        for (int q2 = 0; q2 < 16; ++q2) {
            float4 v = up[q2];
            float a0 = ur[q2].x - v.x; d0 += a0 * a0;
            float a1 = ur[q2].y - v.y; d1 += a1 * a1;
            float a2 = ur[q2].z - v.z; d2 += a2 * a2;
            float a3 = ur[q2].w - v.w; d3 += a3 * a3;
        }
        const float dist = (d0 + d1) + (d2 + d3);
        acc += same ? dist : fmaxf(MVAL - dist, 0.f);
    }

    #pragma unroll
    for (int off = 32; off; off >>= 1) acc += __shfl_down(acc, off, 64);
    if (lane == 0) red[wave] = acc;
    __syncthreads();
    if (t == 0) {
        partial[j] = (float)mult * (red[0] + red[1] + red[2] + red[3]);
        if (e == 0) cntw[c] = mult * cnt;
    }
}

__global__ __launch_bounds__(256) void dsh_final_kernel(
    const float* __restrict__ partial, const int* __restrict__ cntw,
    float* __restrict__ out)
{
    const int t = threadIdx.x;
    const int lane = t & 63, wave = t >> 6;
    __shared__ float redp[4], reda[4];
    __shared__ int   redc[4];

    float p = 0.f, a = 0.f;
    #pragma unroll
    for (int k = 0; k < 4; ++k) {
        const int idx = t + 256 * k;
        if (idx < NCLS * ESPL)            p += partial[idx];
        else if (idx < NCLS * ESPL + NREG) a += partial[idx];
    }
    int cc = (t < NCLS) ? cntw[t] : 0;
    #pragma unroll
    for (int off = 32; off; off >>= 1) {
        p  += __shfl_down(p,  off, 64);
        a  += __shfl_down(a,  off, 64);
        cc += __shfl_down(cc, off, 64);
    }
    if (lane == 0) { redp[wave] = p; reda[wave] = a; redc[wave] = cc; }
    __syncthreads();
    if (t == 0) {
        float P = redp[0] + redp[1] + redp[2] + redp[3];
        float A = reda[0] + reda[1] + reda[2] + reda[3];
        int   S = redc[0] + redc[1] + redc[2] + redc[3];
        out[0] = 0.5f * P / (256.0f * (float)S) + ALPHA * (A * (1.0f / 16384.0f));
    }
}

extern "C" void kernel_launch(void* const* d_in, const int* in_sizes, int n_in,
                              void* d_out, int out_size, void* d_ws, size_t ws_size,
                              hipStream_t stream) {
    const float* u   = (const float*)d_in[0];
    const int*   y   = (const int*)d_in[1];
    const int*   ind = (const int*)d_in[2];
    const float* U   = (const float*)d_in[3];
    const float* Y   = (const float*)d_in[4];
    float* out = (float*)d_out;

    float* partial = (float*)d_ws;                    // [816]
    int*   cntw    = (int*)((char*)d_ws + 4096);      // [100]

    dsh_main_kernel<<<dim3(NCLS * ESPL + NREG), dim3(256), 0, stream>>>(
        u, y, ind, U, Y, partial, cntw);
    dsh_final_kernel<<<dim3(1), dim3(256), 0, stream>>>(partial, cntw, out);
}